// Round 2
// baseline (391.424 us; speedup 1.0000x reference)
//
#include <hip/hip_runtime.h>
#include <math.h>

#define B 8
#define M 8192
#define N 512
#define R 256
#define EPSF 1e-16f

typedef __attribute__((ext_vector_type(8))) short short8;
typedef __attribute__((ext_vector_type(16))) float f32x16;

__device__ __forceinline__ unsigned short bf16_rtn(float f) {
    unsigned int u = __float_as_uint(f);
    u += 0x7FFFu + ((u >> 16) & 1u);
    return (unsigned short)(u >> 16);
}

// async global->LDS, 16B per lane. LDS dest = wave-uniform base + lane*16.
__device__ __forceinline__ void gll16(const unsigned short* g, unsigned short* l) {
    __builtin_amdgcn_global_load_lds(
        (const __attribute__((address_space(1))) unsigned int*)g,
        (__attribute__((address_space(3))) unsigned int*)l, 16, 0, 0);
}

// ---------------------------------------------------------------------------
// Kc: gather centers x[b, inds, :] -> c_hi/c_lo (split bf16) + exact fp32 v2.
// ---------------------------------------------------------------------------
__global__ __launch_bounds__(256) void ekm_kc(
    const float* __restrict__ x, const int* __restrict__ inds,
    unsigned short* __restrict__ c_hi, unsigned short* __restrict__ c_lo,
    float* __restrict__ v2g)
{
    const int t = threadIdx.x, b = blockIdx.y;
    const int r = blockIdx.x * 16 + (t >> 4);
    const int seg = (t & 15) * 32;
    const float* src = x + ((size_t)b * M + inds[r]) * N + seg;
    unsigned short* hd = c_hi + ((size_t)b * R + r) * 512 + seg;
    unsigned short* ld = c_lo + ((size_t)b * R + r) * 512 + seg;
    float vp = 0.f;
#pragma unroll
    for (int c = 0; c < 4; ++c) {
        float4 f0 = *(const float4*)(src + c * 8);
        float4 f1 = *(const float4*)(src + c * 8 + 4);
        float av[8] = {f0.x, f0.y, f0.z, f0.w, f1.x, f1.y, f1.z, f1.w};
        unsigned ph[4], pl[4];
#pragma unroll
        for (int j = 0; j < 4; ++j) {
            vp += av[2*j] * av[2*j] + av[2*j+1] * av[2*j+1];
            unsigned short h0 = bf16_rtn(av[2*j]), h1 = bf16_rtn(av[2*j+1]);
            float r0 = av[2*j]   - __uint_as_float((unsigned)h0 << 16);
            float r1 = av[2*j+1] - __uint_as_float((unsigned)h1 << 16);
            ph[j] = (unsigned)h0 | ((unsigned)h1 << 16);
            pl[j] = (unsigned)bf16_rtn(r0) | ((unsigned)bf16_rtn(r1) << 16);
        }
        *(uint4*)(hd + c * 8) = make_uint4(ph[0], ph[1], ph[2], ph[3]);
        *(uint4*)(ld + c * 8) = make_uint4(pl[0], pl[1], pl[2], pl[3]);
    }
    vp += __shfl_xor(vp, 1); vp += __shfl_xor(vp, 2);
    vp += __shfl_xor(vp, 4); vp += __shfl_xor(vp, 8);
    if ((t & 15) == 0) v2g[b * R + r] = vp;
}

// ---------------------------------------------------------------------------
// K1: split-bf16 32x32x16 MFMA distances + fused softmax.
// K-step 16, A+B double-buffered, 40 KB LDS -> 4 blocks/CU (16 waves), grid
// 1024 = exactly 4/CU (tail-free cohort). Balanced XOR bank swizzles on all
// LDS reads/writes. One barrier per step, counted vmcnt(2).
// b = blockIdx.x & 7 -> each XCD's L2 holds one b's center set (1 MB).
// ---------------------------------------------------------------------------
__global__ __launch_bounds__(256, 4) void ekm_k1(
    const float* __restrict__ x, const float* __restrict__ alpha_p,
    const unsigned short* __restrict__ c_hi, const unsigned short* __restrict__ c_lo,
    const float* __restrict__ v2g, float* __restrict__ u_out,
    unsigned short* __restrict__ uT, unsigned short* __restrict__ xT,
    float* __restrict__ colsum)
{
    __shared__ unsigned short Bh[2][4096], Bl[2][4096];   // 256r x 16k per buf (swizzled)
    __shared__ unsigned short Ah[2][1024], Al[2][1024];   // 64m x 16k per buf (swizzled)

    const int t = threadIdx.x;
    const int b = blockIdx.x & 7;
    const int m0 = (blockIdx.x >> 3) * 64;
    const int w = t >> 6, l = t & 63, col = l & 31, h5 = l >> 5;
    const int arow = t >> 2, kq = t & 3;
    const int swz1 = (col >> 2) & 1;
    // fragment read indices (shorts): slot = (2*row + h5) ^ ((row>>2)&1), idx = slot*8
    const int ari0 = ((col * 2 + h5) ^ swz1) * 8;
    const int ari1 = ((64 + col * 2 + h5) ^ swz1) * 8;
    const int bri0 = ((w * 128 + col * 2 + h5) ^ swz1) * 8;
    const int bri1 = ((w * 128 + 64 + col * 2 + h5) ^ swz1) * 8;
    // A write index: thread holds row=arow, k-quarter kq (4 shorts)
    const int awi = ((arow * 2 + (kq >> 1)) ^ ((arow >> 2) & 1)) * 8 + (kq & 1) * 4;

    const float* ax = x + ((size_t)b * M + m0 + arow) * N + kq * 4;
    // B staging: lane-slot q=i*256+t holds data(row=q>>1, ks=(q&1)^((q>>3)&1))
    const int bso = ((t & 1) ^ ((t >> 3) & 1)) * 8;
    const unsigned short* bhs = c_hi + ((size_t)b * R + (t >> 1)) * 512 + bso;
    const unsigned short* bls = c_lo + ((size_t)b * R + (t >> 1)) * 512 + bso;

    f32x16 acc[2][2];
    acc[0][0] = (f32x16)0.f; acc[0][1] = (f32x16)0.f;
    acc[1][0] = (f32x16)0.f; acc[1][1] = (f32x16)0.f;

    float x2p = 0.f;
    unsigned ph0, ph1, pl0, pl1;
    float4 a0;

    auto convert = [&](void) {   // a0 -> hi/lo bf16 packs, exact x2 accumulation
        float av[4] = {a0.x, a0.y, a0.z, a0.w};
        unsigned hp[2], lp[2];
#pragma unroll
        for (int j = 0; j < 2; ++j) {
            x2p += av[2*j] * av[2*j] + av[2*j+1] * av[2*j+1];
            unsigned short h0 = bf16_rtn(av[2*j]), h1 = bf16_rtn(av[2*j+1]);
            float r0 = av[2*j]   - __uint_as_float((unsigned)h0 << 16);
            float r1 = av[2*j+1] - __uint_as_float((unsigned)h1 << 16);
            hp[j] = (unsigned)h0 | ((unsigned)h1 << 16);
            lp[j] = (unsigned)bf16_rtn(r0) | ((unsigned)bf16_rtn(r1) << 16);
        }
        ph0 = hp[0]; ph1 = hp[1]; pl0 = lp[0]; pl1 = lp[1];
    };

    auto mfma_tile = [&](int c) {
        short8 bh0 = *(const short8*)&Bh[c][bri0];
        short8 bl0 = *(const short8*)&Bl[c][bri0];
        short8 bh1 = *(const short8*)&Bh[c][bri1];
        short8 bl1 = *(const short8*)&Bl[c][bri1];
#pragma unroll
        for (int tm = 0; tm < 2; ++tm) {
            short8 ah = *(const short8*)&Ah[c][tm ? ari1 : ari0];
            short8 al = *(const short8*)&Al[c][tm ? ari1 : ari0];
            acc[tm][0] = __builtin_amdgcn_mfma_f32_32x32x16_bf16(ah, bh0, acc[tm][0], 0, 0, 0);
            acc[tm][0] = __builtin_amdgcn_mfma_f32_32x32x16_bf16(ah, bl0, acc[tm][0], 0, 0, 0);
            acc[tm][0] = __builtin_amdgcn_mfma_f32_32x32x16_bf16(al, bh0, acc[tm][0], 0, 0, 0);
            acc[tm][1] = __builtin_amdgcn_mfma_f32_32x32x16_bf16(ah, bh1, acc[tm][1], 0, 0, 0);
            acc[tm][1] = __builtin_amdgcn_mfma_f32_32x32x16_bf16(ah, bl1, acc[tm][1], 0, 0, 0);
            acc[tm][1] = __builtin_amdgcn_mfma_f32_32x32x16_bf16(al, bh1, acc[tm][1], 0, 0, 0);
        }
    };

    auto xt_store = [&](int c, int tt) {   // xT[tt*16+kk][m0..m0+63], coalesced 8B
        int kk = t >> 4, ms = (t & 15) * 4;
        unsigned short vv[4];
#pragma unroll
        for (int j = 0; j < 4; ++j) {
            int row = ms + j;
            vv[j] = Ah[c][((row * 2 + (kk >> 3)) ^ ((row >> 2) & 1)) * 8 + (kk & 7)];
        }
        *(uint2*)(xT + ((size_t)b * N + tt * 16 + kk) * M + m0 + ms) =
            make_uint2((unsigned)vv[0] | ((unsigned)vv[1] << 16),
                       (unsigned)vv[2] | ((unsigned)vv[3] << 16));
    };

    // ---- prologue: stage tile 0 into buf0, prefetch x for tile 1 ----
    a0 = *(const float4*)(ax);
    convert();
    gll16(bhs,              &Bh[0][t * 8]);
    gll16(bhs + 128 * 512,  &Bh[0][2048 + t * 8]);
    gll16(bls,              &Bl[0][t * 8]);
    gll16(bls + 128 * 512,  &Bl[0][2048 + t * 8]);
    __builtin_amdgcn_sched_barrier(0);
    *(uint2*)&Ah[0][awi] = make_uint2(ph0, ph1);
    *(uint2*)&Al[0][awi] = make_uint2(pl0, pl1);
    a0 = *(const float4*)(ax + 16);
    asm volatile("s_waitcnt vmcnt(1) lgkmcnt(0)" ::: "memory");
    __builtin_amdgcn_s_barrier();
    __builtin_amdgcn_sched_barrier(0);

    // ---- body: compute tile tt from buf c, stage tile tt+1 into buf nb ----
    auto body = [&](int tt, int c, int nb) {
        convert();                                   // tile tt+1 regs -> packs
        gll16(bhs + (tt + 1) * 16,             &Bh[nb][t * 8]);
        gll16(bhs + 128 * 512 + (tt + 1) * 16, &Bh[nb][2048 + t * 8]);
        gll16(bls + (tt + 1) * 16,             &Bl[nb][t * 8]);
        gll16(bls + 128 * 512 + (tt + 1) * 16, &Bl[nb][2048 + t * 8]);
        __builtin_amdgcn_sched_barrier(0);           // glls stay oldest in vmcnt
        *(uint2*)&Ah[nb][awi] = make_uint2(ph0, ph1);
        *(uint2*)&Al[nb][awi] = make_uint2(pl0, pl1);
        const int pf = (tt + 2 < 32 ? tt + 2 : 31) * 16;   // uniform vmem count
        a0 = *(const float4*)(ax + pf);              // prefetch x tile tt+2
        xt_store(c, tt);
        mfma_tile(c);
        // drain the 4 glls (oldest); leave x-prefetch + xT-store in flight
        asm volatile("s_waitcnt vmcnt(2) lgkmcnt(0)" ::: "memory");
        __builtin_amdgcn_s_barrier();
        __builtin_amdgcn_sched_barrier(0);
    };

#pragma unroll 1
    for (int tp = 0; tp < 15; ++tp) {
        body(2 * tp, 0, 1);
        body(2 * tp + 1, 1, 0);
    }
    body(30, 0, 1);
    mfma_tile(1);        // peeled tile 31
    xt_store(1, 31);

    // ---- epilogue (scratch aliases dead LDS) ----
    float* x2s = (float*)&Al[0][0];                   // 256 B (buf0 dead)
    float (*redm)[64] = (float (*)[64])&Bh[0][0];     // 1 KB
    float (*reds)[64] = (float (*)[64])&Bh[0][2048];  // 1 KB

    x2p += __shfl_xor(x2p, 1);
    x2p += __shfl_xor(x2p, 2);
    if (kq == 0) x2s[arow] = x2p;
    __syncthreads();

    const float ia = 1.4426950408889634f / alpha_p[0];  // log2(e)/alpha
    float v2c[2];
#pragma unroll
    for (int tr = 0; tr < 2; ++tr)
        v2c[tr] = v2g[b * R + w * 64 + tr * 32 + col];

    // d = relu(x2 - 2xv + v2); wave-local row min; stage to LDS
#pragma unroll
    for (int tm = 0; tm < 2; ++tm)
#pragma unroll
    for (int reg = 0; reg < 16; ++reg) {
        int rowl = (reg & 3) + 8 * (reg >> 2) + 4 * h5;
        float x2v = x2s[tm * 32 + rowl];
        float mn;
#pragma unroll
        for (int tr = 0; tr < 2; ++tr) {
            float d = x2v - 2.f * acc[tm][tr][reg] + v2c[tr];
            d = fmaxf(d, 0.f);
            acc[tm][tr][reg] = d;
            mn = (tr == 0) ? d : fminf(mn, d);
        }
        mn = fminf(mn, __shfl_xor(mn, 1));
        mn = fminf(mn, __shfl_xor(mn, 2));
        mn = fminf(mn, __shfl_xor(mn, 4));
        mn = fminf(mn, __shfl_xor(mn, 8));
        mn = fminf(mn, __shfl_xor(mn, 16));
        if (col == 0) redm[w][tm * 32 + rowl] = mn;
    }
    __syncthreads();

    // exp + row sum
#pragma unroll
    for (int tm = 0; tm < 2; ++tm)
#pragma unroll
    for (int reg = 0; reg < 16; ++reg) {
        int m = tm * 32 + (reg & 3) + 8 * (reg >> 2) + 4 * h5;
        float mn = fminf(fminf(redm[0][m], redm[1][m]), fminf(redm[2][m], redm[3][m]));
        float s = 0.f;
#pragma unroll
        for (int tr = 0; tr < 2; ++tr) {
            float e = exp2f((mn - acc[tm][tr][reg]) * ia);
            acc[tm][tr][reg] = e;
            s += e;
        }
        s += __shfl_xor(s, 1); s += __shfl_xor(s, 2); s += __shfl_xor(s, 4);
        s += __shfl_xor(s, 8); s += __shfl_xor(s, 16);
        if (col == 0) reds[w][m] = s;
    }
    __syncthreads();

    // normalize, write u (fp32), accumulate colsum, pack uT (bf16)
    float* ub = u_out + ((size_t)b * M + m0) * R + w * 64;
    float cs[2] = {0.f, 0.f};
#pragma unroll
    for (int tm = 0; tm < 2; ++tm)
#pragma unroll
    for (int reg = 0; reg < 16; ++reg) {
        int rowl = (reg & 3) + 8 * (reg >> 2) + 4 * h5;
        int m = tm * 32 + rowl;
        float inv = 1.f / (reds[0][m] + reds[1][m] + reds[2][m] + reds[3][m]);
#pragma unroll
        for (int tr = 0; tr < 2; ++tr) {
            float uu = acc[tm][tr][reg] * inv;
            acc[tm][tr][reg] = uu;
            ub[(size_t)m * R + tr * 32 + col] = uu;
            cs[tr] += uu;
        }
    }
    unsigned short* uTb = uT + ((size_t)b * R + w * 64) * M + m0;
#pragma unroll
    for (int tm = 0; tm < 2; ++tm)
#pragma unroll
    for (int tr = 0; tr < 2; ++tr)
#pragma unroll
    for (int rq = 0; rq < 4; ++rq) {
        uint2 p;
        p.x = (unsigned)bf16_rtn(acc[tm][tr][rq*4+0]) | ((unsigned)bf16_rtn(acc[tm][tr][rq*4+1]) << 16);
        p.y = (unsigned)bf16_rtn(acc[tm][tr][rq*4+2]) | ((unsigned)bf16_rtn(acc[tm][tr][rq*4+3]) << 16);
        *(uint2*)(uTb + (size_t)(tr*32 + col) * M + tm*32 + 8*rq + 4*h5) = p;
    }
    cs[0] += __shfl_xor(cs[0], 32);
    cs[1] += __shfl_xor(cs[1], 32);
    if (h5 == 0) {
        atomicAdd(&colsum[b * R + w * 64 + col], cs[0]);
        atomicAdd(&colsum[b * R + w * 64 + 32 + col], cs[1]);
    }
}

// ---------------------------------------------------------------------------
// K2: part[slab][b][n][r] = sum_{m in slab} xT[n][m]*uT[r][m].
// Quad-buffered K-step 32 (64 KB LDS), stage 3 tiles ahead, counted vmcnt(8)
// -> ~2 bodies of latency cover. XCD-aware block decode: all blocks of one b
// land on one XCD (L2 reuse of xT/uT slices). Balanced XOR bank swizzle.
// ---------------------------------------------------------------------------
__global__ __launch_bounds__(256, 2) void ekm_k2(
    const unsigned short* __restrict__ xT, const unsigned short* __restrict__ uT,
    float* __restrict__ part)
{
    __shared__ unsigned short XA[4][4096], UB[4][4096];   // 128 rows x 32 k per buf

    const int t = threadIdx.x;
    const int lin = blockIdx.x;
    const int xcd = lin & 7, idx = lin >> 3;
    const int ntrt = idx & 7, sb = (xcd << 3) | (idx >> 3);
    const int slab = sb & 7, b = sb >> 3;                 // b == xcd
    const int nt = ntrt >> 1, rt = ntrt & 1;
    const int n0 = nt * 128, r0 = rt * 128;
    const int w = t >> 6, l = t & 63, col = l & 31, h5 = l >> 5;
    const int wn = w >> 1, wr = w & 1;
    const int swz2 = (col >> 1) & 3;

    // staging: lane-slot q=i*256+t holds data(row=q>>2, ks=(q&3)^((q>>3)&3))
    const int srow = t >> 2;
    const int ks = (t & 3) ^ ((t >> 3) & 3);
    const unsigned short* xs = xT + ((size_t)b * N + n0 + srow) * M + (size_t)slab * 1024 + ks * 8;
    const unsigned short* us = uT + ((size_t)b * R + r0 + srow) * M + (size_t)slab * 1024 + ks * 8;

    f32x16 acc[2][2];
    acc[0][0] = (f32x16)0.f; acc[0][1] = (f32x16)0.f;
    acc[1][0] = (f32x16)0.f; acc[1][1] = (f32x16)0.f;

    auto stageK = [&](int tt, unsigned short* xa, unsigned short* ub2) {
        gll16(xs + tt * 32,                  xa + t * 8);
        gll16(xs + tt * 32 + (size_t)64 * M, xa + 2048 + t * 8);
        gll16(us + tt * 32,                  ub2 + t * 8);
        gll16(us + tt * 32 + (size_t)64 * M, ub2 + 2048 + t * 8);
    };
    auto computeK = [&](const unsigned short* xa, const unsigned short* ub2) {
#pragma unroll
        for (int ch = 0; ch < 2; ++ch) {
            const int pc = (ch * 2 + h5) ^ swz2;
            short8 af0 = *(const short8*)&xa[(wn * 64 + col) * 32 + pc * 8];
            short8 af1 = *(const short8*)&xa[(wn * 64 + 32 + col) * 32 + pc * 8];
            short8 bf0 = *(const short8*)&ub2[(wr * 64 + col) * 32 + pc * 8];
            short8 bf1 = *(const short8*)&ub2[(wr * 64 + 32 + col) * 32 + pc * 8];
            acc[0][0] = __builtin_amdgcn_mfma_f32_32x32x16_bf16(af0, bf0, acc[0][0], 0, 0, 0);
            acc[0][1] = __builtin_amdgcn_mfma_f32_32x32x16_bf16(af0, bf1, acc[0][1], 0, 0, 0);
            acc[1][0] = __builtin_amdgcn_mfma_f32_32x32x16_bf16(af1, bf0, acc[1][0], 0, 0, 0);
            acc[1][1] = __builtin_amdgcn_mfma_f32_32x32x16_bf16(af1, bf1, acc[1][1], 0, 0, 0);
        }
    };

    // prologue: stage tiles 0,1,2 (12 glls); wait for tile 0 (leave 8)
    stageK(0, &XA[0][0], &UB[0][0]);
    stageK(1, &XA[1][0], &UB[1][0]);
    stageK(2, &XA[2][0], &UB[2][0]);
    asm volatile("s_waitcnt vmcnt(8)" ::: "memory");
    __builtin_amdgcn_s_barrier();
    __builtin_amdgcn_sched_barrier(0);

#pragma unroll 1
    for (int t4 = 0; t4 < 28; t4 += 4) {
#pragma unroll
        for (int j = 0; j < 4; ++j) {
            const int cb = j & 3, nb = (j + 3) & 3;
            stageK(t4 + j + 3, &XA[nb][0], &UB[nb][0]);
            __builtin_amdgcn_sched_barrier(0);
            computeK(&XA[cb][0], &UB[cb][0]);
            asm volatile("s_waitcnt vmcnt(8)" ::: "memory");
            __builtin_amdgcn_s_barrier();
            __builtin_amdgcn_sched_barrier(0);
        }
    }
    stageK(31, &XA[3][0], &UB[3][0]);
    __builtin_amdgcn_sched_barrier(0);
    computeK(&XA[0][0], &UB[0][0]);          // tile 28
    asm volatile("s_waitcnt vmcnt(8)" ::: "memory");
    __builtin_amdgcn_s_barrier();
    __builtin_amdgcn_sched_barrier(0);
    computeK(&XA[1][0], &UB[1][0]);          // tile 29
    asm volatile("s_waitcnt vmcnt(4)" ::: "memory");
    __builtin_amdgcn_s_barrier();
    __builtin_amdgcn_sched_barrier(0);
    computeK(&XA[2][0], &UB[2][0]);          // tile 30
    asm volatile("s_waitcnt vmcnt(0)" ::: "memory");
    __builtin_amdgcn_s_barrier();
    __builtin_amdgcn_sched_barrier(0);
    computeK(&XA[3][0], &UB[3][0]);          // tile 31

    float* pb = part + (size_t)slab * ((size_t)B * N * R) + (size_t)b * N * R;
#pragma unroll
    for (int tm = 0; tm < 2; ++tm)
#pragma unroll
    for (int reg = 0; reg < 16; ++reg) {
        int n = n0 + wn*64 + tm*32 + (reg & 3) + 8*(reg >> 2) + 4*h5;
#pragma unroll
        for (int tr = 0; tr < 2; ++tr)
            pb[(size_t)n * R + r0 + wr*64 + tr*32 + col] = acc[tm][tr][reg];
    }
}

// ---------------------------------------------------------------------------
// Kred: v = (sum of 8 partial slabs) / (colsum + eps), float4 per thread.
// ---------------------------------------------------------------------------
__global__ __launch_bounds__(256) void ekm_red(
    const float* __restrict__ part, const float* __restrict__ colsum,
    float* __restrict__ v_out)
{
    size_t o = ((size_t)blockIdx.x * 256 + threadIdx.x) * 4;
    float sx = 0.f, sy = 0.f, sz = 0.f, sw = 0.f;
#pragma unroll
    for (int sl = 0; sl < 8; ++sl) {
        float4 p = *(const float4*)(part + (size_t)sl * B * N * R + o);
        sx += p.x; sy += p.y; sz += p.z; sw += p.w;
    }
    int b = (int)(o >> 17);           // N*R = 131072
    int r = (int)(o & (R - 1));
    float4 cs = *(const float4*)(colsum + b * R + r);
    float4 vo;
    vo.x = sx / (cs.x + EPSF);
    vo.y = sy / (cs.y + EPSF);
    vo.z = sz / (cs.z + EPSF);
    vo.w = sw / (cs.w + EPSF);
    *(float4*)(v_out + o) = vo;
}

extern "C" void kernel_launch(void* const* d_in, const int* in_sizes, int n_in,
                              void* d_out, int out_size, void* d_ws, size_t ws_size,
                              hipStream_t stream) {
    const float* x     = (const float*)d_in[0];
    const float* alpha = (const float*)d_in[1];
    const int*   inds  = (const int*)d_in[2];

    float* u_out = (float*)d_out;                    // B*M*R fp32
    float* v_out = u_out + (size_t)B * M * R;        // B*N*R fp32

    char* ws = (char*)d_ws;
    const size_t CH = (size_t)B * R * 512 * 2;       // 2 MB   c_hi / c_lo
    unsigned short* c_hi   = (unsigned short*)ws;
    unsigned short* c_lo   = (unsigned short*)(ws + CH);
    float*          v2g    = (float*)(ws + 2 * CH);
    float*          colsum = (float*)(ws + 2 * CH + (size_t)B * R * 4);
    char* p = ws + 2 * CH + 2 * (size_t)B * R * 4;
    unsigned short* xT = (unsigned short*)p;          p += (size_t)B * N * M * 2;  // 67 MB
    unsigned short* uT = (unsigned short*)p;          p += (size_t)B * R * M * 2;  // 33.5 MB
    float*          part = (float*)p;                 // 8 * B*N*R * 4 = 33.5 MB

    hipMemsetAsync(colsum, 0, (size_t)B * R * sizeof(float), stream);

    ekm_kc<<<dim3(16, B), 256, 0, stream>>>(x, inds, c_hi, c_lo, v2g);
    ekm_k1<<<dim3(1024), 256, 0, stream>>>(x, alpha, c_hi, c_lo, v2g,
                                           u_out, uT, xT, colsum);
    ekm_k2<<<dim3(512), 256, 0, stream>>>(xT, uT, part);
    ekm_red<<<(B * N * R / 4) / 256, 256, 0, stream>>>(part, colsum, v_out);
}

// Round 3
// 341.805 us; speedup vs baseline: 1.1452x; 1.1452x over previous
//
#include <hip/hip_runtime.h>
#include <math.h>

#define B 8
#define M 8192
#define N 512
#define R 256
#define EPSF 1e-16f

typedef __attribute__((ext_vector_type(8))) short short8;
typedef __attribute__((ext_vector_type(16))) float f32x16;

__device__ __forceinline__ unsigned short bf16_rtn(float f) {
    unsigned int u = __float_as_uint(f);
    u += 0x7FFFu + ((u >> 16) & 1u);
    return (unsigned short)(u >> 16);
}

// async global->LDS, 16B per lane. LDS dest = wave-uniform base + lane*16.
__device__ __forceinline__ void gll16(const unsigned short* g, unsigned short* l) {
    __builtin_amdgcn_global_load_lds(
        (const __attribute__((address_space(1))) unsigned int*)g,
        (__attribute__((address_space(3))) unsigned int*)l, 16, 0, 0);
}

// ---------------------------------------------------------------------------
// Kc: gather centers x[b, inds, :] -> c_hi/c_lo (split bf16) + exact fp32 v2.
// ---------------------------------------------------------------------------
__global__ __launch_bounds__(256) void ekm_kc(
    const float* __restrict__ x, const int* __restrict__ inds,
    unsigned short* __restrict__ c_hi, unsigned short* __restrict__ c_lo,
    float* __restrict__ v2g)
{
    const int t = threadIdx.x, b = blockIdx.y;
    const int r = blockIdx.x * 16 + (t >> 4);
    const int seg = (t & 15) * 32;
    const float* src = x + ((size_t)b * M + inds[r]) * N + seg;
    unsigned short* hd = c_hi + ((size_t)b * R + r) * 512 + seg;
    unsigned short* ld = c_lo + ((size_t)b * R + r) * 512 + seg;
    float vp = 0.f;
#pragma unroll
    for (int c = 0; c < 4; ++c) {
        float4 f0 = *(const float4*)(src + c * 8);
        float4 f1 = *(const float4*)(src + c * 8 + 4);
        float av[8] = {f0.x, f0.y, f0.z, f0.w, f1.x, f1.y, f1.z, f1.w};
        unsigned ph[4], pl[4];
#pragma unroll
        for (int j = 0; j < 4; ++j) {
            vp += av[2*j] * av[2*j] + av[2*j+1] * av[2*j+1];
            unsigned short h0 = bf16_rtn(av[2*j]), h1 = bf16_rtn(av[2*j+1]);
            float r0 = av[2*j]   - __uint_as_float((unsigned)h0 << 16);
            float r1 = av[2*j+1] - __uint_as_float((unsigned)h1 << 16);
            ph[j] = (unsigned)h0 | ((unsigned)h1 << 16);
            pl[j] = (unsigned)bf16_rtn(r0) | ((unsigned)bf16_rtn(r1) << 16);
        }
        *(uint4*)(hd + c * 8) = make_uint4(ph[0], ph[1], ph[2], ph[3]);
        *(uint4*)(ld + c * 8) = make_uint4(pl[0], pl[1], pl[2], pl[3]);
    }
    vp += __shfl_xor(vp, 1); vp += __shfl_xor(vp, 2);
    vp += __shfl_xor(vp, 4); vp += __shfl_xor(vp, 8);
    if ((t & 15) == 0) v2g[b * R + r] = vp;
}

// ---------------------------------------------------------------------------
// K1: split-bf16 32x32x16 MFMA distances + fused softmax.
// R0's proven 2-barrier K-step-32 structure, with:
//  - A tiles at stride 32 + chunk-XOR f(row)=(row>>3)&3 (fixes the 16-way
//    bank conflict in xt_store's scalar reads; frag reads stay at b128 floor)
//  - epilogue scratch aliased onto dead LDS
//  => LDS exactly 40960 B -> 4 blocks/CU (16 waves), grid 1024 = tail-free.
// ---------------------------------------------------------------------------
__global__ __launch_bounds__(256, 4) void ekm_k1(
    const float* __restrict__ x, const float* __restrict__ alpha_p,
    const unsigned short* __restrict__ c_hi, const unsigned short* __restrict__ c_lo,
    const float* __restrict__ v2g, float* __restrict__ u_out,
    unsigned short* __restrict__ uT, unsigned short* __restrict__ xT,
    float* __restrict__ colsum)
{
    __shared__ unsigned short Ah[64 * 32], Al[64 * 32];   // 4 KB each, swizzled
    __shared__ unsigned short Bh[256 * 32], Bl[256 * 32]; // 16 KB each, swizzled
    // total LDS = 40960 B exactly -> 4 blocks/CU

    const int t = threadIdx.x;
    const int b = blockIdx.y;
    const int m0 = blockIdx.x * 64;
    const int w = t >> 6, l = t & 63, col = l & 31, h5 = l >> 5;
    const int arow = t >> 2, kch = t & 3;
    const int cswz = (t & 3) ^ ((t >> 3) & 3);   // B source chunk for gll
    const int pswz = (col >> 1) & 3;             // B fragment-read chunk XOR
    const int aswz = (col >> 3) & 3;             // A fragment-read chunk XOR
    const int awi = arow * 32 + (kch ^ ((arow >> 3) & 3)) * 8;  // A write slot

    const float* ax = x + ((size_t)b * M + m0 + arow) * N + kch * 8;
    const unsigned short* bhs = c_hi + ((size_t)b * R + (t >> 2)) * 512 + cswz * 8;
    const unsigned short* bls = c_lo + ((size_t)b * R + (t >> 2)) * 512 + cswz * 8;

    f32x16 acc[2][2];
    acc[0][0] = (f32x16)0.f; acc[0][1] = (f32x16)0.f;
    acc[1][0] = (f32x16)0.f; acc[1][1] = (f32x16)0.f;

    float x2p = 0.f;
    float4 a0 = *(const float4*)(ax);
    float4 a1 = *(const float4*)(ax + 4);

    for (int k0 = 0; k0 < N; k0 += 32) {
        // convert prefetched A (fp32 -> hi/lo bf16), exact x2 accumulation
        x2p += a0.x*a0.x + a0.y*a0.y + a0.z*a0.z + a0.w*a0.w
             + a1.x*a1.x + a1.y*a1.y + a1.z*a1.z + a1.w*a1.w;
        float av[8] = {a0.x, a0.y, a0.z, a0.w, a1.x, a1.y, a1.z, a1.w};
        unsigned ph[4], pl[4];
#pragma unroll
        for (int j = 0; j < 4; ++j) {
            unsigned short h0 = bf16_rtn(av[2*j]), h1 = bf16_rtn(av[2*j+1]);
            float r0 = av[2*j]   - __uint_as_float((unsigned)h0 << 16);
            float r1 = av[2*j+1] - __uint_as_float((unsigned)h1 << 16);
            ph[j] = (unsigned)h0 | ((unsigned)h1 << 16);
            pl[j] = (unsigned)bf16_rtn(r0) | ((unsigned)bf16_rtn(r1) << 16);
        }
        __syncthreads();   // previous tile fully consumed
#pragma unroll
        for (int i = 0; i < 4; ++i) {
            gll16(bhs + k0 + i * (64 * 512), Bh + i * 2048 + t * 8);
            gll16(bls + k0 + i * (64 * 512), Bl + i * 2048 + t * 8);
        }
        *(uint4*)&Ah[awi] = make_uint4(ph[0], ph[1], ph[2], ph[3]);
        *(uint4*)&Al[awi] = make_uint4(pl[0], pl[1], pl[2], pl[3]);
        __syncthreads();   // drains gll (vmcnt) + LDS writes

        // prefetch next A AFTER the drain barrier -> hidden behind MFMA section
        if (k0 + 32 < N) {
            a0 = *(const float4*)(ax + k0 + 32);
            a1 = *(const float4*)(ax + k0 + 36);
        }

        // xT slab: [k0+kk][m0..m0+63], coalesced 16B stores.
        // LDS reads now hit 16 distinct banks (4-way), was 4 banks (16-way).
        {
            int kk = t >> 3, ms = (t & 7) * 8;
            unsigned short vv[8];
#pragma unroll
            for (int i = 0; i < 8; ++i) {
                int row = ms + i;
                vv[i] = Ah[row * 32 + (((kk >> 3) ^ ((row >> 3) & 3)) << 3) + (kk & 7)];
            }
            *(uint4*)(xT + ((size_t)b * N + k0 + kk) * M + m0 + ms) =
                make_uint4((unsigned)vv[0] | ((unsigned)vv[1] << 16),
                           (unsigned)vv[2] | ((unsigned)vv[3] << 16),
                           (unsigned)vv[4] | ((unsigned)vv[5] << 16),
                           (unsigned)vv[6] | ((unsigned)vv[7] << 16));
        }

#pragma unroll
        for (int half = 0; half < 2; ++half) {
            const int pa = (half * 2 + h5) ^ aswz;   // A physical chunk
            const int pc = (half * 2 + h5) ^ pswz;   // B physical chunk
            short8 ah[2], al2[2], bh[2], bl2[2];
#pragma unroll
            for (int tm = 0; tm < 2; ++tm) {
                ah[tm]  = *(const short8*)&Ah[(tm*32 + col) * 32 + pa * 8];
                al2[tm] = *(const short8*)&Al[(tm*32 + col) * 32 + pa * 8];
            }
#pragma unroll
            for (int tr = 0; tr < 2; ++tr) {
                bh[tr]  = *(const short8*)&Bh[(w*64 + tr*32 + col) * 32 + pc * 8];
                bl2[tr] = *(const short8*)&Bl[(w*64 + tr*32 + col) * 32 + pc * 8];
            }
#pragma unroll
            for (int tm = 0; tm < 2; ++tm)
#pragma unroll
            for (int tr = 0; tr < 2; ++tr) {
                acc[tm][tr] = __builtin_amdgcn_mfma_f32_32x32x16_bf16(ah[tm],  bh[tr],  acc[tm][tr], 0, 0, 0);
                acc[tm][tr] = __builtin_amdgcn_mfma_f32_32x32x16_bf16(ah[tm],  bl2[tr], acc[tm][tr], 0, 0, 0);
                acc[tm][tr] = __builtin_amdgcn_mfma_f32_32x32x16_bf16(al2[tm], bh[tr],  acc[tm][tr], 0, 0, 0);
            }
        }
    }

    // ---- epilogue (scratch aliases now-dead LDS) ----
    __syncthreads();                                  // all loop LDS reads done
    float* x2s = (float*)&Ah[0];                      // 256 B
    float (*redm)[64] = (float (*)[64])&Al[0];        // 1 KB
    float (*reds)[64] = (float (*)[64])&Bh[0];        // 1 KB

    x2p += __shfl_xor(x2p, 1);
    x2p += __shfl_xor(x2p, 2);
    if (kch == 0) x2s[arow] = x2p;
    __syncthreads();

    const float ia = 1.4426950408889634f / alpha_p[0];  // log2(e)/alpha
    float v2c[2];
#pragma unroll
    for (int tr = 0; tr < 2; ++tr)
        v2c[tr] = v2g[b * R + w * 64 + tr * 32 + col];

    // d = relu(x2 - 2xv + v2); wave-local row min; stage to LDS
#pragma unroll
    for (int tm = 0; tm < 2; ++tm)
#pragma unroll
    for (int reg = 0; reg < 16; ++reg) {
        int rowl = (reg & 3) + 8 * (reg >> 2) + 4 * h5;
        float x2v = x2s[tm * 32 + rowl];
        float mn;
#pragma unroll
        for (int tr = 0; tr < 2; ++tr) {
            float d = x2v - 2.f * acc[tm][tr][reg] + v2c[tr];
            d = fmaxf(d, 0.f);
            acc[tm][tr][reg] = d;
            mn = (tr == 0) ? d : fminf(mn, d);
        }
        mn = fminf(mn, __shfl_xor(mn, 1));
        mn = fminf(mn, __shfl_xor(mn, 2));
        mn = fminf(mn, __shfl_xor(mn, 4));
        mn = fminf(mn, __shfl_xor(mn, 8));
        mn = fminf(mn, __shfl_xor(mn, 16));
        if (col == 0) redm[w][tm * 32 + rowl] = mn;
    }
    __syncthreads();

    // exp + row sum
#pragma unroll
    for (int tm = 0; tm < 2; ++tm)
#pragma unroll
    for (int reg = 0; reg < 16; ++reg) {
        int m = tm * 32 + (reg & 3) + 8 * (reg >> 2) + 4 * h5;
        float mn = fminf(fminf(redm[0][m], redm[1][m]), fminf(redm[2][m], redm[3][m]));
        float s = 0.f;
#pragma unroll
        for (int tr = 0; tr < 2; ++tr) {
            float e = exp2f((mn - acc[tm][tr][reg]) * ia);
            acc[tm][tr][reg] = e;
            s += e;
        }
        s += __shfl_xor(s, 1); s += __shfl_xor(s, 2); s += __shfl_xor(s, 4);
        s += __shfl_xor(s, 8); s += __shfl_xor(s, 16);
        if (col == 0) reds[w][m] = s;
    }
    __syncthreads();

    // normalize, write u (fp32), accumulate colsum, pack uT (bf16)
    float* ub = u_out + ((size_t)b * M + m0) * R + w * 64;
    float cs[2] = {0.f, 0.f};
#pragma unroll
    for (int tm = 0; tm < 2; ++tm)
#pragma unroll
    for (int reg = 0; reg < 16; ++reg) {
        int rowl = (reg & 3) + 8 * (reg >> 2) + 4 * h5;
        int m = tm * 32 + rowl;
        float inv = 1.f / (reds[0][m] + reds[1][m] + reds[2][m] + reds[3][m]);
#pragma unroll
        for (int tr = 0; tr < 2; ++tr) {
            float uu = acc[tm][tr][reg] * inv;
            acc[tm][tr][reg] = uu;
            ub[(size_t)m * R + tr * 32 + col] = uu;
            cs[tr] += uu;
        }
    }
    unsigned short* uTb = uT + ((size_t)b * R + w * 64) * M + m0;
#pragma unroll
    for (int tm = 0; tm < 2; ++tm)
#pragma unroll
    for (int tr = 0; tr < 2; ++tr)
#pragma unroll
    for (int rq = 0; rq < 4; ++rq) {
        uint2 p;
        p.x = (unsigned)bf16_rtn(acc[tm][tr][rq*4+0]) | ((unsigned)bf16_rtn(acc[tm][tr][rq*4+1]) << 16);
        p.y = (unsigned)bf16_rtn(acc[tm][tr][rq*4+2]) | ((unsigned)bf16_rtn(acc[tm][tr][rq*4+3]) << 16);
        *(uint2*)(uTb + (size_t)(tr*32 + col) * M + tm*32 + 8*rq + 4*h5) = p;
    }
    cs[0] += __shfl_xor(cs[0], 32);
    cs[1] += __shfl_xor(cs[1], 32);
    if (h5 == 0) {
        atomicAdd(&colsum[b * R + w * 64 + col], cs[0]);
        atomicAdd(&colsum[b * R + w * 64 + 32 + col], cs[1]);
    }
}

// ---------------------------------------------------------------------------
// K2: part[slab][b][n][r] = sum_{m in slab} xT[n][m]*uT[r][m].
// R0 version (proven; restructuring measured neutral in R1/R2).
// ---------------------------------------------------------------------------
__global__ __launch_bounds__(256, 2) void ekm_k2(
    const unsigned short* __restrict__ xT, const unsigned short* __restrict__ uT,
    float* __restrict__ part)
{
    __shared__ unsigned short XA[128 * 32], UB[128 * 32];
    const int t = threadIdx.x;
    const int nt = blockIdx.x >> 1, rt = blockIdx.x & 1;
    const int slab = blockIdx.y, b = blockIdx.z;
    const int n0 = nt * 128, r0 = rt * 128;
    const int w = t >> 6, l = t & 63, col = l & 31, h5 = l >> 5;
    const int wn = w >> 1, wr = w & 1;
    const int cswz = (t & 3) ^ ((t >> 3) & 3);
    const int pswz = (col >> 1) & 3;

    const unsigned short* xs = xT + ((size_t)b * N + n0 + (t >> 2)) * M + slab * 1024 + cswz * 8;
    const unsigned short* us = uT + ((size_t)b * R + r0 + (t >> 2)) * M + slab * 1024 + cswz * 8;

    f32x16 acc[2][2];
    acc[0][0] = (f32x16)0.f; acc[0][1] = (f32x16)0.f;
    acc[1][0] = (f32x16)0.f; acc[1][1] = (f32x16)0.f;

    for (int k0 = 0; k0 < 1024; k0 += 32) {
        __syncthreads();
#pragma unroll
        for (int i = 0; i < 2; ++i) {
            gll16(xs + k0 + (size_t)i * 64 * M, XA + i * 2048 + t * 8);
            gll16(us + k0 + (size_t)i * 64 * M, UB + i * 2048 + t * 8);
        }
        __syncthreads();
#pragma unroll
        for (int half = 0; half < 2; ++half) {
            const int pc = (half * 2 + h5) ^ pswz;
            short8 af[2], bf2[2];
#pragma unroll
            for (int tm = 0; tm < 2; ++tm)
                af[tm] = *(const short8*)&XA[(wn*64 + tm*32 + col) * 32 + pc*8];
#pragma unroll
            for (int tr = 0; tr < 2; ++tr)
                bf2[tr] = *(const short8*)&UB[(wr*64 + tr*32 + col) * 32 + pc*8];
#pragma unroll
            for (int tm = 0; tm < 2; ++tm)
#pragma unroll
            for (int tr = 0; tr < 2; ++tr)
                acc[tm][tr] = __builtin_amdgcn_mfma_f32_32x32x16_bf16(af[tm], bf2[tr], acc[tm][tr], 0, 0, 0);
        }
    }

    float* pb = part + (size_t)slab * ((size_t)B * N * R) + (size_t)b * N * R;
#pragma unroll
    for (int tm = 0; tm < 2; ++tm)
#pragma unroll
    for (int reg = 0; reg < 16; ++reg) {
        int n = n0 + wn*64 + tm*32 + (reg & 3) + 8*(reg >> 2) + 4*h5;
#pragma unroll
        for (int tr = 0; tr < 2; ++tr)
            pb[(size_t)n * R + r0 + wr*64 + tr*32 + col] = acc[tm][tr][reg];
    }
}

// ---------------------------------------------------------------------------
// Kred: v = (sum of 8 partial slabs) / (colsum + eps), float4 per thread.
// ---------------------------------------------------------------------------
__global__ __launch_bounds__(256) void ekm_red(
    const float* __restrict__ part, const float* __restrict__ colsum,
    float* __restrict__ v_out)
{
    size_t o = ((size_t)blockIdx.x * 256 + threadIdx.x) * 4;
    float sx = 0.f, sy = 0.f, sz = 0.f, sw = 0.f;
#pragma unroll
    for (int sl = 0; sl < 8; ++sl) {
        float4 p = *(const float4*)(part + (size_t)sl * B * N * R + o);
        sx += p.x; sy += p.y; sz += p.z; sw += p.w;
    }
    int b = (int)(o >> 17);           // N*R = 131072
    int r = (int)(o & (R - 1));
    float4 cs = *(const float4*)(colsum + b * R + r);
    float4 vo;
    vo.x = sx / (cs.x + EPSF);
    vo.y = sy / (cs.y + EPSF);
    vo.z = sz / (cs.z + EPSF);
    vo.w = sw / (cs.w + EPSF);
    *(float4*)(v_out + o) = vo;
}

extern "C" void kernel_launch(void* const* d_in, const int* in_sizes, int n_in,
                              void* d_out, int out_size, void* d_ws, size_t ws_size,
                              hipStream_t stream) {
    const float* x     = (const float*)d_in[0];
    const float* alpha = (const float*)d_in[1];
    const int*   inds  = (const int*)d_in[2];

    float* u_out = (float*)d_out;                    // B*M*R fp32
    float* v_out = u_out + (size_t)B * M * R;        // B*N*R fp32

    char* ws = (char*)d_ws;
    const size_t CH = (size_t)B * R * 512 * 2;       // 2 MB   c_hi / c_lo
    unsigned short* c_hi   = (unsigned short*)ws;
    unsigned short* c_lo   = (unsigned short*)(ws + CH);
    float*          v2g    = (float*)(ws + 2 * CH);
    float*          colsum = (float*)(ws + 2 * CH + (size_t)B * R * 4);
    char* p = ws + 2 * CH + 2 * (size_t)B * R * 4;
    unsigned short* xT = (unsigned short*)p;          p += (size_t)B * N * M * 2;  // 67 MB
    unsigned short* uT = (unsigned short*)p;          p += (size_t)B * R * M * 2;  // 33.5 MB
    float*          part = (float*)p;                 // 8 * B*N*R * 4 = 33.5 MB

    hipMemsetAsync(colsum, 0, (size_t)B * R * sizeof(float), stream);

    ekm_kc<<<dim3(16, B), 256, 0, stream>>>(x, inds, c_hi, c_lo, v2g);
    ekm_k1<<<dim3(M / 64, B), 256, 0, stream>>>(x, alpha, c_hi, c_lo, v2g,
                                                u_out, uT, xT, colsum);
    ekm_k2<<<dim3(8, 8, B), 256, 0, stream>>>(xT, uT, part);
    ekm_red<<<(B * N * R / 4) / 256, 256, 0, stream>>>(part, colsum, v_out);
}